// Round 7
// baseline (109.270 us; speedup 1.0000x reference)
//
#include <hip/hip_runtime.h>
#include <hip/hip_bf16.h>

// ---------------------------------------------------------------------------
// Clebsch-Gordan coefficients (L_MAX = 3), computed per-term at compile time.
// Each term is its own small constexpr evaluation (avoids clang's per-
// expression constexpr step limit).
// ---------------------------------------------------------------------------
constexpr int L_MAX = 3;
constexpr int NUM_ORDERS = (L_MAX + 1) * (L_MAX + 1);  // 16
constexpr int C = 64;

using f32x4 = __attribute__((ext_vector_type(4))) float;

constexpr double cfact(int n) {
    double r = 1.0;
    for (int i = 2; i <= n; ++i) r *= (double)i;
    return r;
}

constexpr double csqrt(double x) {
    if (x <= 0.0) return 0.0;
    double g = x > 1.0 ? x : 1.0;
    for (int i = 0; i < 60; ++i) g = 0.5 * (g + x / g);
    return g;
}

constexpr int cmax2(int a, int b) { return a > b ? a : b; }
constexpr int cmin2(int a, int b) { return a < b ? a : b; }
constexpr int cabs(int a) { return a < 0 ? -a : a; }

constexpr double cg_coeff(int l1, int m1, int l2, int m2, int l, int m) {
    if (m1 + m2 != m) return 0.0;
    double pref = csqrt((double)(2 * l + 1) * cfact(l + l1 - l2) * cfact(l - l1 + l2)
                        * cfact(l1 + l2 - l) / cfact(l1 + l2 + l + 1));
    pref *= csqrt(cfact(l + m) * cfact(l - m) * cfact(l1 - m1)
                  * cfact(l1 + m1) * cfact(l2 - m2) * cfact(l2 + m2));
    int kmin = cmax2(0, cmax2(l2 - l - m1, l1 + m2 - l));
    int kmax = cmin2(l1 + l2 - l, cmin2(l1 - m1, l2 + m2));
    double s = 0.0;
    for (int k = kmin; k <= kmax; ++k) {
        double sign = (k % 2 == 0) ? 1.0 : -1.0;
        s += sign / (cfact(k) * cfact(l1 + l2 - l - k) * cfact(l1 - m1 - k)
                     * cfact(l2 + m2 - k) * cfact(l - l2 + m1 + k)
                     * cfact(l - l1 - m2 + k));
    }
    return pref * s;
}

// --- template-recursive loop nest: emit one fma per nonzero CG term --------

template <int L, int L1, int L2, int M, int M1>
struct TermEmit {
    __device__ static __forceinline__ void run(const float* a, const float* b, float* acc) {
        constexpr int M2 = M - M1;
        constexpr double Vd = (M2 >= -L2 && M2 <= L2)
                                  ? cg_coeff(L1, M1, L2, M2, L, M) : 0.0;
        constexpr float V = (float)Vd;
        if constexpr (V != 0.0f) {
            acc[L * L + L + M] = fmaf(
                V, a[L1 * L1 + L1 + M1] * b[L2 * L2 + L2 + M2],
                acc[L * L + L + M]);
        }
    }
};

template <int L, int L1, int L2, int M, int M1, bool Done = (M1 > L1)>
struct LoopM1 {
    __device__ static __forceinline__ void run(const float* a, const float* b, float* acc) {
        TermEmit<L, L1, L2, M, M1>::run(a, b, acc);
        LoopM1<L, L1, L2, M, M1 + 1>::run(a, b, acc);
    }
};
template <int L, int L1, int L2, int M, int M1>
struct LoopM1<L, L1, L2, M, M1, true> {
    __device__ static __forceinline__ void run(const float*, const float*, float*) {}
};

template <int L, int L1, int L2, int M, bool Done = (M > L)>
struct LoopM {
    __device__ static __forceinline__ void run(const float* a, const float* b, float* acc) {
        LoopM1<L, L1, L2, M, -L1>::run(a, b, acc);
        LoopM<L, L1, L2, M + 1>::run(a, b, acc);
    }
};
template <int L, int L1, int L2, int M>
struct LoopM<L, L1, L2, M, true> {
    __device__ static __forceinline__ void run(const float*, const float*, float*) {}
};

template <int L, int L1, int L2, bool Done = (L2 > cmin2(L_MAX, L + L1))>
struct LoopL2 {
    __device__ static __forceinline__ void run(const float* a, const float* b, float* acc) {
        LoopM<L, L1, L2, -L>::run(a, b, acc);
        LoopL2<L, L1, L2 + 1>::run(a, b, acc);
    }
};
template <int L, int L1, int L2>
struct LoopL2<L, L1, L2, true> {
    __device__ static __forceinline__ void run(const float*, const float*, float*) {}
};

template <int L, int L1, bool Done = (L1 > L_MAX)>
struct LoopL1 {
    __device__ static __forceinline__ void run(const float* a, const float* b, float* acc) {
        LoopL2<L, L1, cabs(L - L1)>::run(a, b, acc);
        LoopL1<L, L1 + 1>::run(a, b, acc);
    }
};
template <int L, int L1>
struct LoopL1<L, L1, true> {
    __device__ static __forceinline__ void run(const float*, const float*, float*) {}
};

template <int L, bool Done = (L > L_MAX)>
struct LoopL {
    __device__ static __forceinline__ void run(const float* a, const float* b, float* acc) {
        LoopL1<L, 0>::run(a, b, acc);
        LoopL<L + 1>::run(a, b, acc);
    }
};
template <int L>
struct LoopL<L, true> {
    __device__ static __forceinline__ void run(const float*, const float*, float*) {}
};

// ---------------------------------------------------------------------------
// One wave per batch row. All global I/O is 16 B/lane dwordx4 (1 KiB per
// wave instruction — identical profile to the 6.3 TB/s copy benchmark):
// 8 loads stage the row's x1+x2 (8 KB) into a wave-private LDS slab, each
// thread re-reads its 16-order fragments (ds_read_b32, lane-contiguous ->
// free 2-way bank aliasing), computes the 478 unrolled CG terms, writes acc
// back to the same slab, and the wave stores with 4 dwordx4. No barriers:
// LDS regions are wave-private and same-wave DS ops are in-order.
// ~100 VGPR (under the 128 spill cliff from R5), 32 KB LDS/block.
// ---------------------------------------------------------------------------
__global__ __launch_bounds__(256) void tp_cg_kernel(
        const float* __restrict__ x1, const float* __restrict__ x2,
        float* __restrict__ out, int n_batch) {
    constexpr int ROW = NUM_ORDERS * C;      // 1024 floats per batch row
    constexpr int ROWQ = ROW / 4;            // 256 f32x4 per row

    __shared__ float lds[4][2 * ROW];        // per-wave slab: a-row + b-row
    const int lane = threadIdx.x & 63;
    const int wib = threadIdx.x >> 6;        // wave index in block
    const int n = (blockIdx.x * 256 + threadIdx.x) >> 6;  // one row per wave
    if (n >= n_batch) return;

    float* __restrict__ wl = lds[wib];
    const long base = (long)n * ROW;

    // --- stage x1,x2 rows into LDS with 16 B/lane loads -------------------
    const f32x4* __restrict__ s1 = reinterpret_cast<const f32x4*>(x1 + base);
    const f32x4* __restrict__ s2 = reinterpret_cast<const f32x4*>(x2 + base);
    f32x4* __restrict__ la = reinterpret_cast<f32x4*>(wl);          // [256]
    f32x4* __restrict__ lb = la + ROWQ;                             // [256]
#pragma unroll
    for (int k = 0; k < 4; ++k) la[k * 64 + lane] = s1[k * 64 + lane];
#pragma unroll
    for (int k = 0; k < 4; ++k) lb[k * 64 + lane] = s2[k * 64 + lane];

    // --- per-thread fragments: channel = lane ------------------------------
    float a[NUM_ORDERS], b[NUM_ORDERS], acc[NUM_ORDERS];
#pragma unroll
    for (int m = 0; m < NUM_ORDERS; ++m) {
        a[m] = wl[m * C + lane];
        b[m] = wl[ROW + m * C + lane];
        acc[m] = 0.0f;
    }

    LoopL<0>::run(a, b, acc);

    // --- re-layout acc through the (now dead) a-region, store 16 B/lane ---
#pragma unroll
    for (int m = 0; m < NUM_ORDERS; ++m) wl[m * C + lane] = acc[m];

    f32x4* __restrict__ o = reinterpret_cast<f32x4*>(out + base);
#pragma unroll
    for (int k = 0; k < 4; ++k) o[k * 64 + lane] = la[k * 64 + lane];
}

extern "C" void kernel_launch(void* const* d_in, const int* in_sizes, int n_in,
                              void* d_out, int out_size, void* d_ws, size_t ws_size,
                              hipStream_t stream) {
    const float* x1 = (const float*)d_in[0];
    const float* x2 = (const float*)d_in[1];
    // d_in[2..5] (CG_vals, M1, M2, Mseg) are compile-time constants -> ignored.
    float* out = (float*)d_out;

    const int n_batch = in_sizes[0] / (NUM_ORDERS * C);  // 8192
    const long total_threads = (long)n_batch * 64;       // one wave per row
    const int block = 256;
    const int grid = (int)((total_threads + block - 1) / block);

    tp_cg_kernel<<<grid, block, 0, stream>>>(x1, x2, out, n_batch);
}